// Round 2
// baseline (257.809 us; speedup 1.0000x reference)
//
#include <hip/hip_runtime.h>
#include <math.h>

// ---------------- shared gate machinery (compile-time wires) ----------------
// Wire w = bit (3-w) of flat index (wire 0 = MSB), matching reference layout.

template<int W>
__device__ __forceinline__ void apply_ry(float2* st, float c, float s) {
    constexpr int M = 1 << (3 - W);
    #pragma unroll
    for (int j = 0; j < 16; ++j) {
        if ((j & M) == 0) {
            float2 a0 = st[j], a1 = st[j | M];
            st[j]     = make_float2(c * a0.x - s * a1.x, c * a0.y - s * a1.y);
            st[j | M] = make_float2(s * a0.x + c * a1.x, s * a0.y + c * a1.y);
        }
    }
}

template<int W>
__device__ __forceinline__ void apply_rz(float2* st, float c, float s) {
    constexpr int M = 1 << (3 - W);
    #pragma unroll
    for (int j = 0; j < 16; ++j) {
        float sg = (j & M) ? s : -s;
        float2 a = st[j];
        st[j] = make_float2(c * a.x - sg * a.y, c * a.y + sg * a.x);
    }
}

template<int C, int T>
__device__ __forceinline__ void apply_cnot(float2* st) {
    constexpr int MC = 1 << (3 - C), MT = 1 << (3 - T);
    #pragma unroll
    for (int j = 0; j < 16; ++j) {
        if ((j & MC) != 0 && (j & MT) == 0) {
            float2 tmp = st[j];
            st[j] = st[j | MT];
            st[j | MT] = tmp;
        }
    }
}

template<int A, int Bq>
__device__ __forceinline__ void ansatz(float2* st, const float* pc, const float* ps) {
    apply_ry<A >(st, pc[0], ps[0]);
    apply_rz<A >(st, pc[1], ps[1]);
    apply_ry<Bq>(st, pc[2], ps[2]);
    apply_rz<Bq>(st, pc[3], ps[3]);
    apply_cnot<A, Bq>(st);
    apply_ry<A >(st, pc[4], ps[4]);
    apply_rz<A >(st, pc[5], ps[5]);
    apply_ry<Bq>(st, pc[6], ps[6]);
}

// ---------------- setup: fold ansatz into 4 x (9x9) bilinear forms ----------
// out_w = h01^T B_w h23,  h01 = r0 (x) r1,  h23 = r2 (x) r3,
// r_q = (c_q^2, c_q s_q, s_q^2) with half-angle c,s of the encoder RY.
// B_w[m] = sum over (j,k) with m_q = j_q + k_q of A_w[j][k],
// A_w = Re(U^dag Z_w U).

__global__ void qsetup_kernel(const float* __restrict__ params,
                              float* __restrict__ Bmat /* [4][81] */) {
    __shared__ float2 U[16][16];  // U[m][b]: amplitude m of basis column b

    int b = threadIdx.x;
    if (b < 16) {
        float pc[2][7], ps[2][7];
        for (int l = 0; l < 2; ++l)
            for (int k = 0; k < 7; ++k)
                sincosf(0.5f * params[l * 7 + k], &ps[l][k], &pc[l][k]);

        float2 st[16];
        for (int j = 0; j < 16; ++j) st[j] = make_float2(0.f, 0.f);
        st[b] = make_float2(1.f, 0.f);

        for (int l = 0; l < 2; ++l) {
            ansatz<0, 1>(st, pc[l], ps[l]);
            ansatz<1, 2>(st, pc[l], ps[l]);
            ansatz<2, 3>(st, pc[l], ps[l]);
            ansatz<3, 0>(st, pc[l], ps[l]);
        }
        for (int m = 0; m < 16; ++m) U[m][b] = st[m];
    }
    __syncthreads();

    int w = threadIdx.x;
    if (w < 4) {
        float Bw[81];
        for (int t = 0; t < 81; ++t) Bw[t] = 0.f;
        for (int j = 0; j < 16; ++j) {
            for (int k = 0; k < 16; ++k) {
                float a = 0.f;
                for (int m = 0; m < 16; ++m) {
                    float z = ((m >> (3 - w)) & 1) ? -1.f : 1.f;
                    a += z * (U[m][j].x * U[m][k].x + U[m][j].y * U[m][k].y);
                }
                int m0 = ((j >> 3) & 1) + ((k >> 3) & 1);
                int m1 = ((j >> 2) & 1) + ((k >> 2) & 1);
                int m2 = ((j >> 1) & 1) + ((k >> 1) & 1);
                int m3 = ((j >> 0) & 1) + ((k >> 0) & 1);
                Bw[(m0 * 3 + m1) * 9 + (m2 * 3 + m3)] += a;
            }
        }
        for (int t = 0; t < 81; ++t) Bmat[w * 81 + t] = Bw[t];
    }
}

// ---------------- main: per-element bilinear evaluation ---------------------

__global__ __launch_bounds__(256) void qmain_kernel(
        const float* __restrict__ patches,
        const float* __restrict__ Bmat,
        float* __restrict__ out, int B) {
    int i = blockIdx.x * blockDim.x + threadIdx.x;
    if (i >= B) return;

    float4 x4 = reinterpret_cast<const float4*>(patches)[i];
    float xs[4] = {x4.x, x4.y, x4.z, x4.w};

    float r[4][3];
    #pragma unroll
    for (int w = 0; w < 4; ++w) {
        float sig = 1.0f / (1.0f + __expf(-xs[w]));
        float half = sig * (0.5f * (float)M_PI);
        float s, c;
        __sincosf(half, &s, &c);
        r[w][0] = c * c;
        r[w][1] = c * s;
        r[w][2] = s * s;
    }

    float h01[9], h23[9];
    #pragma unroll
    for (int a = 0; a < 3; ++a) {
        #pragma unroll
        for (int b = 0; b < 3; ++b) {
            h01[a * 3 + b] = r[0][a] * r[1][b];
            h23[a * 3 + b] = r[2][a] * r[3][b];
        }
    }

    float o[4];
    #pragma unroll
    for (int w = 0; w < 4; ++w) {
        float acc = 0.f;
        #pragma unroll
        for (int j = 0; j < 9; ++j) {
            float t = 0.f;
            #pragma unroll
            for (int k = 0; k < 9; ++k)
                t = fmaf(Bmat[w * 81 + j * 9 + k], h23[k], t);
            acc = fmaf(h01[j], t, acc);
        }
        o[w] = acc;
    }

    reinterpret_cast<float4*>(out)[i] = make_float4(o[0], o[1], o[2], o[3]);
}

extern "C" void kernel_launch(void* const* d_in, const int* in_sizes, int n_in,
                              void* d_out, int out_size, void* d_ws, size_t ws_size,
                              hipStream_t stream) {
    const float* patches = (const float*)d_in[0];
    const float* params  = (const float*)d_in[1];
    float* out  = (float*)d_out;
    float* Bmat = (float*)d_ws;  // 4*81 floats = 1296 B of scratch

    qsetup_kernel<<<1, 64, 0, stream>>>(params, Bmat);

    int B = in_sizes[0] / 4;
    int block = 256;
    int grid = (B + block - 1) / block;
    qmain_kernel<<<grid, block, 0, stream>>>(patches, Bmat, out, B);
}

// Round 3
// 23.482 us; speedup vs baseline: 10.9789x; 10.9789x over previous
//
#include <hip/hip_runtime.h>
#include <math.h>

// ---------------- shared gate machinery (compile-time wires) ----------------
// Wire w = bit (3-w) of flat index (wire 0 = MSB), matching reference layout.

template<int W>
__device__ __forceinline__ void apply_ry(float2* st, float c, float s) {
    constexpr int M = 1 << (3 - W);
    #pragma unroll
    for (int j = 0; j < 16; ++j) {
        if ((j & M) == 0) {
            float2 a0 = st[j], a1 = st[j | M];
            st[j]     = make_float2(c * a0.x - s * a1.x, c * a0.y - s * a1.y);
            st[j | M] = make_float2(s * a0.x + c * a1.x, s * a0.y + c * a1.y);
        }
    }
}

template<int W>
__device__ __forceinline__ void apply_rz(float2* st, float c, float s) {
    constexpr int M = 1 << (3 - W);
    #pragma unroll
    for (int j = 0; j < 16; ++j) {
        float sg = (j & M) ? s : -s;
        float2 a = st[j];
        st[j] = make_float2(c * a.x - sg * a.y, c * a.y + sg * a.x);
    }
}

template<int C, int T>
__device__ __forceinline__ void apply_cnot(float2* st) {
    constexpr int MC = 1 << (3 - C), MT = 1 << (3 - T);
    #pragma unroll
    for (int j = 0; j < 16; ++j) {
        if ((j & MC) != 0 && (j & MT) == 0) {
            float2 tmp = st[j];
            st[j] = st[j | MT];
            st[j | MT] = tmp;
        }
    }
}

template<int A, int Bq>
__device__ __forceinline__ void ansatz(float2* st, const float* pc, const float* ps) {
    apply_ry<A >(st, pc[0], ps[0]);
    apply_rz<A >(st, pc[1], ps[1]);
    apply_ry<Bq>(st, pc[2], ps[2]);
    apply_rz<Bq>(st, pc[3], ps[3]);
    apply_cnot<A, Bq>(st);
    apply_ry<A >(st, pc[4], ps[4]);
    apply_rz<A >(st, pc[5], ps[5]);
    apply_ry<Bq>(st, pc[6], ps[6]);
}

// ---------------- setup: fold ansatz into 4 x (9x9) bilinear forms ----------
// out_w = h01^T B_w h23,  h01 = r0 (x) r1,  h23 = r2 (x) r3,
// r_q = (c_q^2, c_q s_q, s_q^2) with half-angle c,s of the encoder RY.
// B_w[m] = sum over (j,k) with m_q = j_q + k_q of A_w[j][k],
// A_w = Re(U^dag Z_w U).
// Parallel version: 1024 threads; thread (w,j,k) computes scalar A_w[j][k]
// and LDS-atomicAdds it into Bs. No runtime-indexed private arrays.

__global__ __launch_bounds__(1024) void qsetup_kernel(
        const float* __restrict__ params,
        float* __restrict__ Bmat /* [4][81] */) {
    __shared__ float2 U[16][16];  // U[m][b]: amplitude m of basis column b
    __shared__ float Bs[324];

    int tid = threadIdx.x;
    if (tid < 324) Bs[tid] = 0.f;

    if (tid < 16) {
        float pc[2][7], ps[2][7];
        #pragma unroll
        for (int l = 0; l < 2; ++l)
            #pragma unroll
            for (int k = 0; k < 7; ++k)
                __sincosf(0.5f * params[l * 7 + k], &ps[l][k], &pc[l][k]);

        float2 st[16];
        #pragma unroll
        for (int j = 0; j < 16; ++j) st[j] = make_float2(0.f, 0.f);
        st[tid] = make_float2(1.f, 0.f);

        #pragma unroll
        for (int l = 0; l < 2; ++l) {
            ansatz<0, 1>(st, pc[l], ps[l]);
            ansatz<1, 2>(st, pc[l], ps[l]);
            ansatz<2, 3>(st, pc[l], ps[l]);
            ansatz<3, 0>(st, pc[l], ps[l]);
        }
        #pragma unroll
        for (int m = 0; m < 16; ++m) U[m][tid] = st[m];
    }
    __syncthreads();

    int w = tid >> 8, j = (tid >> 4) & 15, k = tid & 15;
    float a = 0.f;
    #pragma unroll
    for (int m = 0; m < 16; ++m) {
        float z = ((m >> (3 - w)) & 1) ? -1.f : 1.f;
        a += z * (U[m][j].x * U[m][k].x + U[m][j].y * U[m][k].y);
    }
    int m0 = ((j >> 3) & 1) + ((k >> 3) & 1);
    int m1 = ((j >> 2) & 1) + ((k >> 2) & 1);
    int m2 = ((j >> 1) & 1) + ((k >> 1) & 1);
    int m3 = ((j >> 0) & 1) + ((k >> 0) & 1);
    atomicAdd(&Bs[w * 81 + (m0 * 3 + m1) * 9 + (m2 * 3 + m3)], a);
    __syncthreads();

    if (tid < 324) Bmat[tid] = Bs[tid];
}

// ---------------- main: per-element bilinear evaluation ---------------------

__global__ __launch_bounds__(256) void qmain_kernel(
        const float* __restrict__ patches,
        const float* __restrict__ Bmat,
        float* __restrict__ out, int B) {
    int i = blockIdx.x * blockDim.x + threadIdx.x;
    if (i >= B) return;

    float4 x4 = reinterpret_cast<const float4*>(patches)[i];
    float xs[4] = {x4.x, x4.y, x4.z, x4.w};

    float r[4][3];
    #pragma unroll
    for (int w = 0; w < 4; ++w) {
        float sig = 1.0f / (1.0f + __expf(-xs[w]));
        float half = sig * (0.5f * (float)M_PI);
        float s, c;
        __sincosf(half, &s, &c);
        r[w][0] = c * c;
        r[w][1] = c * s;
        r[w][2] = s * s;
    }

    float h01[9], h23[9];
    #pragma unroll
    for (int a = 0; a < 3; ++a) {
        #pragma unroll
        for (int b = 0; b < 3; ++b) {
            h01[a * 3 + b] = r[0][a] * r[1][b];
            h23[a * 3 + b] = r[2][a] * r[3][b];
        }
    }

    float o[4];
    #pragma unroll
    for (int w = 0; w < 4; ++w) {
        float acc = 0.f;
        #pragma unroll
        for (int j = 0; j < 9; ++j) {
            float t = 0.f;
            #pragma unroll
            for (int k = 0; k < 9; ++k)
                t = fmaf(Bmat[w * 81 + j * 9 + k], h23[k], t);
            acc = fmaf(h01[j], t, acc);
        }
        o[w] = acc;
    }

    reinterpret_cast<float4*>(out)[i] = make_float4(o[0], o[1], o[2], o[3]);
}

extern "C" void kernel_launch(void* const* d_in, const int* in_sizes, int n_in,
                              void* d_out, int out_size, void* d_ws, size_t ws_size,
                              hipStream_t stream) {
    const float* patches = (const float*)d_in[0];
    const float* params  = (const float*)d_in[1];
    float* out  = (float*)d_out;
    float* Bmat = (float*)d_ws;  // 324 floats = 1296 B of scratch

    qsetup_kernel<<<1, 1024, 0, stream>>>(params, Bmat);

    int B = in_sizes[0] / 4;
    int block = 256;
    int grid = (B + block - 1) / block;
    qmain_kernel<<<grid, block, 0, stream>>>(patches, Bmat, out, B);
}

// Round 4
// 16.036 us; speedup vs baseline: 16.0768x; 1.4643x over previous
//
#include <hip/hip_runtime.h>
#include <math.h>

// ============================================================================
// Algebra (verified in R2/R3): out_w = h01^T B_w h23, where
//   h01 = r0 (x) r1, h23 = r2 (x) r3, r_q = (c^2, c*s, s^2) of encoder RY
//   half-angle; B_w is the 9x9 binned form of A_w = Re(U^dag Z_w U) and
//   U = the fixed 2-layer ansatz (params batch-uniform).
// ============================================================================

// ---------------- setup: shuffle-parallel basis-column simulation -----------
// Lane l of wave w holds amplitude m = l&15 of basis column j = 4w + (l>>4).
// Gate masks 1/2/4/8 keep __shfl_xor within each 16-lane group.

template<int W>
__device__ __forceinline__ void ry_sh(float& x, float& y, float c, float s, int m) {
    constexpr int M = 1 << (3 - W);
    float px = __shfl_xor(x, M, 64);
    float py = __shfl_xor(y, M, 64);
    float sg = (m & M) ? s : -s;
    x = fmaf(sg, px, c * x);
    y = fmaf(sg, py, c * y);
}

template<int W>
__device__ __forceinline__ void rz_sh(float& x, float& y, float c, float s, int m) {
    constexpr int M = 1 << (3 - W);
    float sg = (m & M) ? -s : s;   // bit0: *(c - i s); bit1: *(c + i s)
    float nx = fmaf(sg, y, c * x);
    float ny = fmaf(-sg, x, c * y);
    x = nx; y = ny;
}

template<int C, int T>
__device__ __forceinline__ void cnot_sh(float& x, float& y, int m) {
    constexpr int MC = 1 << (3 - C), MT = 1 << (3 - T);
    float px = __shfl_xor(x, MT, 64);
    float py = __shfl_xor(y, MT, 64);
    bool ctl = (m & MC) != 0;
    x = ctl ? px : x;
    y = ctl ? py : y;
}

template<int A, int Bq>
__device__ __forceinline__ void ansatz_sh(float& x, float& y,
                                          const float* pc, const float* ps, int m) {
    ry_sh<A >(x, y, pc[0], ps[0], m);
    rz_sh<A >(x, y, pc[1], ps[1], m);
    ry_sh<Bq>(x, y, pc[2], ps[2], m);
    rz_sh<Bq>(x, y, pc[3], ps[3], m);
    cnot_sh<A, Bq>(x, y, m);
    ry_sh<A >(x, y, pc[4], ps[4], m);
    rz_sh<A >(x, y, pc[5], ps[5], m);
    ry_sh<Bq>(x, y, pc[6], ps[6], m);
}

__global__ __launch_bounds__(256) void qsetup_kernel(
        const float* __restrict__ params,
        float* __restrict__ Bmat /* [4][81] */) {
    __shared__ float2 U[16][17];   // [m][j], padded: conflict-free r/w
    __shared__ float Bs[324];

    int tid = threadIdx.x;
    for (int t = tid; t < 324; t += 256) Bs[t] = 0.f;

    // ---- phase 1: simulate 16 basis columns across 4 waves ----
    {
        float pc[2][7], ps[2][7];
        #pragma unroll
        for (int l = 0; l < 2; ++l)
            #pragma unroll
            for (int k = 0; k < 7; ++k)
                __sincosf(0.5f * params[l * 7 + k], &ps[l][k], &pc[l][k]);

        int m = tid & 15;          // amplitude index within column
        int j = tid >> 4;          // basis column (0..15), 4 per wave
        float x = (m == j) ? 1.f : 0.f;
        float y = 0.f;

        #pragma unroll
        for (int l = 0; l < 2; ++l) {
            ansatz_sh<0, 1>(x, y, pc[l], ps[l], m);
            ansatz_sh<1, 2>(x, y, pc[l], ps[l], m);
            ansatz_sh<2, 3>(x, y, pc[l], ps[l], m);
            ansatz_sh<3, 0>(x, y, pc[l], ps[l], m);
        }
        U[m][j] = make_float2(x, y);
    }
    __syncthreads();

    // ---- phase 2: thread (j,k) computes a(j,k,m) once, bins 4 wires ----
    {
        int j = tid >> 4, k = tid & 15;
        float a0 = 0.f, a1 = 0.f, a2 = 0.f, a3 = 0.f;
        #pragma unroll
        for (int m = 0; m < 16; ++m) {
            float2 uj = U[m][j], uk = U[m][k];
            float a = uj.x * uk.x + uj.y * uk.y;
            a0 += (m & 8) ? -a : a;   // wire 0 = bit 3
            a1 += (m & 4) ? -a : a;
            a2 += (m & 2) ? -a : a;
            a3 += (m & 1) ? -a : a;
        }
        int m0 = ((j >> 3) & 1) + ((k >> 3) & 1);
        int m1 = ((j >> 2) & 1) + ((k >> 2) & 1);
        int m2 = ((j >> 1) & 1) + ((k >> 1) & 1);
        int m3 = ((j >> 0) & 1) + ((k >> 0) & 1);
        int base = (m0 * 3 + m1) * 9 + (m2 * 3 + m3);
        atomicAdd(&Bs[  0 + base], a0);
        atomicAdd(&Bs[ 81 + base], a1);
        atomicAdd(&Bs[162 + base], a2);
        atomicAdd(&Bs[243 + base], a3);
    }
    __syncthreads();

    for (int t = tid; t < 324; t += 256) Bmat[t] = Bs[t];
}

// ---------------- main: per-element bilinear evaluation ---------------------

__global__ __launch_bounds__(256) void qmain_kernel(
        const float* __restrict__ patches,
        const float* __restrict__ Bmat,
        float* __restrict__ out, int B) {
    int i = blockIdx.x * blockDim.x + threadIdx.x;
    if (i >= B) return;

    float4 x4 = reinterpret_cast<const float4*>(patches)[i];
    float xs[4] = {x4.x, x4.y, x4.z, x4.w};

    float r[4][3];
    #pragma unroll
    for (int w = 0; w < 4; ++w) {
        float sig = 1.0f / (1.0f + __expf(-xs[w]));
        float half = sig * (0.5f * (float)M_PI);
        float s, c;
        __sincosf(half, &s, &c);
        r[w][0] = c * c;
        r[w][1] = c * s;
        r[w][2] = s * s;
    }

    float h01[9], h23[9];
    #pragma unroll
    for (int a = 0; a < 3; ++a) {
        #pragma unroll
        for (int b = 0; b < 3; ++b) {
            h01[a * 3 + b] = r[0][a] * r[1][b];
            h23[a * 3 + b] = r[2][a] * r[3][b];
        }
    }

    float o[4];
    #pragma unroll
    for (int w = 0; w < 4; ++w) {
        float acc = 0.f;
        #pragma unroll
        for (int j = 0; j < 9; ++j) {
            float t = 0.f;
            #pragma unroll
            for (int k = 0; k < 9; ++k)
                t = fmaf(Bmat[w * 81 + j * 9 + k], h23[k], t);
            acc = fmaf(h01[j], t, acc);
        }
        o[w] = acc;
    }

    reinterpret_cast<float4*>(out)[i] = make_float4(o[0], o[1], o[2], o[3]);
}

extern "C" void kernel_launch(void* const* d_in, const int* in_sizes, int n_in,
                              void* d_out, int out_size, void* d_ws, size_t ws_size,
                              hipStream_t stream) {
    const float* patches = (const float*)d_in[0];
    const float* params  = (const float*)d_in[1];
    float* out  = (float*)d_out;
    float* Bmat = (float*)d_ws;  // 324 floats = 1296 B of scratch

    qsetup_kernel<<<1, 256, 0, stream>>>(params, Bmat);

    int B = in_sizes[0] / 4;
    int block = 256;
    int grid = (B + block - 1) / block;
    qmain_kernel<<<grid, block, 0, stream>>>(patches, Bmat, out, B);
}